// Round 8
// baseline (769.410 us; speedup 1.0000x reference)
//
#include <hip/hip_runtime.h>
#include <cstdint>
#include <cstddef>

// B=4, S=2048, D=1024, U=1024 self-attention, fp32 in/out.
// R8: in-register pipelined K-loop: frag-read BEFORE freeing LDS, DMA issue
//     aged through the MFMA burst (single 32KB LDS buffer, 2 barriers).
//     BK=64, 128x128 tile, 8-way XOR swizzle, global_load_lds staging.
//     fp16 2-term split (KCAT=2048) for QK-proj + scores; V 1-term.
//     Wave-per-row softmax; vectorized splits.

typedef unsigned short ushort_t;
typedef _Float16 half_t;
typedef __attribute__((ext_vector_type(8))) short short8;
typedef __attribute__((ext_vector_type(4))) float floatx4;

__device__ inline unsigned short h2u(half_t h) {
  union { half_t h; unsigned short u; } v; v.h = h; return v.u;
}

// async 16B global -> LDS (DMA). LDS dest = wave-uniform base + lane*16 (HW).
__device__ __forceinline__ void gload16(const half_t* g, half_t* l) {
  __builtin_amdgcn_global_load_lds(
      (const __attribute__((address_space(1))) unsigned int*)g,
      (__attribute__((address_space(3))) unsigned int*)l, 16, 0, 0);
}

// ---------- constants ----------
#define MX 8192       // B*S
#define KCAT 2048     // 2*D (fp16 2-term split-concatenated K dim)

// ws byte offsets (regions reused across phases; S overwrites xcat/wt)
#define XCAT_OFF 0UL                  // half [8192][2048] = 33554432 B
#define WT_OFF   50331648UL           // half 3 x [1024][2048] = 12582912 B
#define S_OFF    0UL                  // float [4][2048][2048] = 67108864 B
#define QCAT_OFF 69206016UL           // half [8192][2048]
#define KCAT_OFF 119537664UL          // half [8192][2048]
#define VT_OFF   169869312UL          // half [4][1024][2048] = 16777216 B
#define WS_NEED  186646528UL

// ---------- K1a: split inputs X -> Xcat = [xh | xl] (fp16), 4 elems/thread ----------
__global__ __launch_bounds__(256) void k_split_x(const float* __restrict__ X,
                                                 half_t* __restrict__ xcat) {
  long long i4 = ((long long)blockIdx.x * 256 + threadIdx.x) * 4;  // over 8192*1024
  float4 x = *(const float4*)(X + i4);
  half_t h0 = (half_t)x.x, h1 = (half_t)x.y, h2 = (half_t)x.z, h3 = (half_t)x.w;
  half_t l0 = (half_t)(x.x - (float)h0), l1 = (half_t)(x.y - (float)h1);
  half_t l2 = (half_t)(x.z - (float)h2), l3 = (half_t)(x.w - (float)h3);
  long long row = i4 >> 10;
  int col = (int)(i4 & 1023);
  half_t* r = xcat + row * KCAT;
  uint2 hi, lo;
  hi.x = (unsigned)h2u(h0) | ((unsigned)h2u(h1) << 16);
  hi.y = (unsigned)h2u(h2) | ((unsigned)h2u(h3) << 16);
  lo.x = (unsigned)h2u(l0) | ((unsigned)h2u(l1) << 16);
  lo.y = (unsigned)h2u(l2) | ((unsigned)h2u(l3) << 16);
  *(uint2*)(r + col) = hi;
  *(uint2*)(r + col + 1024) = lo;
}

// ---------- K1b: transpose W -> WT_cat = [Wh | Wh] per weight (V: [Wh|Wh] too,
// but V GEMM only consumes first 1024 cols) ----------
__global__ __launch_bounds__(256) void k_split_wt(const float* __restrict__ Wq,
                                                  const float* __restrict__ Wk,
                                                  const float* __restrict__ Wv,
                                                  half_t* __restrict__ wt) {
  __shared__ float tile[64][65];
  const float* W = (blockIdx.z == 0) ? Wq : ((blockIdx.z == 1) ? Wk : Wv);
  half_t* out = wt + (size_t)blockIdx.z * 1024 * KCAT;
  int d0 = blockIdx.y * 64, u0 = blockIdx.x * 64;
  int t = threadIdx.x;
  int tr = t >> 6, tc = t & 63;
  for (int r = 0; r < 64; r += 4)
    tile[r + tr][tc] = W[(size_t)(d0 + r + tr) * 1024 + (u0 + tc)];
  __syncthreads();
  for (int r = 0; r < 64; r += 4) {
    int urow = r + tr, dcol = tc;
    float x = tile[dcol][urow];  // = WT[u0+urow][d0+dcol]
    half_t h = (half_t)x;
    half_t* o = out + (size_t)(u0 + urow) * KCAT + d0;
    o[dcol] = h;
    o[dcol + 1024] = h;
  }
}

// ---------- GEMM: C[m][n] = sum_k A[m][k] * Bt[n][k] ----------
// 128x128 tile, 4 waves each 64x64 (4x4 frags of mfma_f32_16x16x32_f16), BK=64.
// Pipelined single-buffer K-loop:
//   [B1: drain DMA (aged by prev MFMA burst)] [frag reads -> regs] [B2]
//   [issue DMA for k+1] [32 MFMA]
// Tile = 128 rows x 64 halves = 1024 chunks of 16B; thread t stages chunks
// t+256s, s=0..3, per matrix. Swizzle: LDS chunk (row,pos) holds global
// chunk q = pos ^ (row&7).
enum { EP_F32 = 0, EP_QK = 1, EP_VT = 2 };

template <int MODE>
__global__ __launch_bounds__(256, 4) void k_gemm(
    const half_t* __restrict__ A, long long aBatch, int lda,
    const half_t* __restrict__ Bt, long long bBatch, int ldb,
    void* __restrict__ Cout, long long cBatch, int ldc, int K,
    half_t* __restrict__ CoutK) {
  __shared__ __align__(16) half_t As[128 * 64];
  __shared__ __align__(16) half_t Bs[128 * 64];
  const int t = threadIdx.x;
  const int z = blockIdx.z;
  A += (long long)z * aBatch;
  Bt += (long long)z * bBatch;
  const int m0 = blockIdx.y * 128, n0 = blockIdx.x * 128;

  const int w = t >> 6, l = t & 63;
  const int lr = l & 15, quad = l >> 4;
  const int wm = (w >> 1) * 64, wn = (w & 1) * 64;

  const floatx4 fz = {0.f, 0.f, 0.f, 0.f};
  floatx4 acc[4][4];
#pragma unroll
  for (int i = 0; i < 4; i++)
#pragma unroll
    for (int j = 0; j < 4; j++) acc[i][j] = fz;

  // staging pointers: chunk c = s*256+t -> row c>>3, lds pos c&7,
  // global col-chunk (c&7) ^ ((c>>3)&7)
  const half_t* Ap[4];
  const half_t* Bp[4];
  half_t* ldsA[4];
  half_t* ldsB[4];
#pragma unroll
  for (int s = 0; s < 4; s++) {
    int c = s * 256 + t;
    int row = c >> 3, gq = (c & 7) ^ ((c >> 3) & 7);
    Ap[s] = A + (long long)(m0 + row) * lda + gq * 8;
    Bp[s] = Bt + (long long)(n0 + row) * ldb + gq * 8;
    ldsA[s] = &As[(s * 256 + w * 64) * 8];  // wave-uniform; lane adds l*16B
    ldsB[s] = &Bs[(s * 256 + w * 64) * 8];
  }

  // fragment read positions: k-step s, quad-chunk q = s*4+quad,
  // pos p = q ^ (lr&7); addr = row*64 + p*8 halves
  const int p0 = quad ^ (lr & 7);
  const int p1 = (quad + 4) ^ (lr & 7);
  const int arow = (wm + lr) * 64, brow = (wn + lr) * 64;

  // prologue: issue tile-0 DMA
#pragma unroll
  for (int s = 0; s < 4; s++) {
    gload16(Ap[s], ldsA[s]);
    gload16(Bp[s], ldsB[s]);
  }

  for (int kb = 0; kb < K; kb += 64) {
    __syncthreads();  // drain: tile-kb DMA visible (aged by prev MFMA burst)
    short8 af[2][4], bfg[2][4];
#pragma unroll
    for (int s = 0; s < 2; s++) {
      const int pp = s ? p1 : p0;
#pragma unroll
      for (int j = 0; j < 4; j++) bfg[s][j] = *(const short8*)&Bs[brow + j * 1024 + pp * 8];
#pragma unroll
      for (int i = 0; i < 4; i++) af[s][i] = *(const short8*)&As[arow + i * 1024 + pp * 8];
    }
    __syncthreads();  // all waves' frag reads done -> LDS overwritable
    int kn = kb + 64;
    if (kn < K) {     // issue next tile's DMA; it ages through the MFMA burst
#pragma unroll
      for (int s = 0; s < 4; s++) {
        gload16(Ap[s] + kn, ldsA[s]);
        gload16(Bp[s] + kn, ldsB[s]);
      }
    }
#pragma unroll
    for (int s = 0; s < 2; s++)
#pragma unroll
      for (int i = 0; i < 4; i++)
#pragma unroll
        for (int j = 0; j < 4; j++)
          acc[i][j] = __builtin_amdgcn_mfma_f32_16x16x32_f16(af[s][i], bfg[s][j], acc[i][j], 0, 0, 0);
  }

  // epilogue: D[row = quad*4 + r][col = lr] per (i,j) subtile
#pragma unroll
  for (int i = 0; i < 4; i++) {
#pragma unroll
    for (int j = 0; j < 4; j++) {
#pragma unroll
      for (int r = 0; r < 4; r++) {
        int grow = m0 + wm + i * 16 + quad * 4 + r;
        int gcol = n0 + wn + j * 16 + lr;
        float v = acc[i][j][r];
        if (MODE == EP_F32) {
          float* C = (float*)Cout + (long long)z * cBatch;
          C[(long long)grow * ldc + gcol] = v;
        } else if (MODE == EP_QK) {  // gcol in [0,2048); sel uniform per (block,j)
          int sel = gcol >> 10;
          int ucol = gcol & 1023;
          half_t h = (half_t)v;
          if (sel == 0) {        // Q = [qh | ql]
            half_t* pq = (half_t*)Cout + (long long)grow * KCAT;
            pq[ucol] = h;
            pq[ucol + 1024] = (half_t)(v - (float)h);
          } else {               // K = [kh | kh]
            half_t* pk = CoutK + (long long)grow * KCAT;
            pk[ucol] = h;
            pk[ucol + 1024] = h;
          }
        } else {  // EP_VT: V^T[b][u][s] = V[b*2048+s][u]
          half_t* C = (half_t*)Cout;
          int b = grow >> 11, s = grow & 2047;
          C[((long long)b * 1024 + gcol) * 2048 + s] = (half_t)v;
        }
      }
    }
  }
}

// ---------- softmax: one wave per row, no barriers. fp32[2048] -> fp16[2048] ----------
__global__ __launch_bounds__(256) void k_softmax(float* __restrict__ Sbuf) {
  int wv = threadIdx.x >> 6, ln = threadIdx.x & 63;
  long long row = (long long)blockIdx.x * 4 + wv;  // grid 2048 -> rows 0..8191
  float* p = Sbuf + row * 2048;
  float4 v[8];
#pragma unroll
  for (int j = 0; j < 8; j++) v[j] = ((const float4*)p)[ln + 64 * j];
  float m = -1e30f;
#pragma unroll
  for (int j = 0; j < 8; j++)
    m = fmaxf(m, fmaxf(fmaxf(v[j].x, v[j].y), fmaxf(v[j].z, v[j].w)));
#pragma unroll
  for (int off = 32; off; off >>= 1) m = fmaxf(m, __shfl_xor(m, off));
  float s = 0.f;
#pragma unroll
  for (int j = 0; j < 8; j++) {
    v[j].x = __expf(v[j].x - m); v[j].y = __expf(v[j].y - m);
    v[j].z = __expf(v[j].z - m); v[j].w = __expf(v[j].w - m);
    s += (v[j].x + v[j].y) + (v[j].z + v[j].w);
  }
#pragma unroll
  for (int off = 32; off; off >>= 1) s += __shfl_xor(s, off);
  float inv = 1.0f / s;
#pragma unroll
  for (int j = 0; j < 8; j++) {
    uint2 wo;
    wo.x = (unsigned)h2u((half_t)(v[j].x * inv)) | ((unsigned)h2u((half_t)(v[j].y * inv)) << 16);
    wo.y = (unsigned)h2u((half_t)(v[j].z * inv)) | ((unsigned)h2u((half_t)(v[j].w * inv)) << 16);
    ((uint2*)p)[ln + 64 * j] = wo;  // fp16 elements 4*(ln+64j)..+3
  }
}

// ---------- host launch ----------
extern "C" void kernel_launch(void* const* d_in, const int* in_sizes, int n_in,
                              void* d_out, int out_size, void* d_ws, size_t ws_size,
                              hipStream_t stream) {
  (void)in_sizes; (void)n_in; (void)out_size;
  if (ws_size < WS_NEED) return;  // output stays poisoned -> visible failure

  const float* X = (const float*)d_in[0];
  const float* Wq = (const float*)d_in[1];
  const float* Wk = (const float*)d_in[2];
  const float* Wv = (const float*)d_in[3];
  char* ws = (char*)d_ws;
  half_t* xcat = (half_t*)(ws + XCAT_OFF);
  half_t* wt = (half_t*)(ws + WT_OFF);
  float* Sbuf = (float*)(ws + S_OFF);
  half_t* qcat = (half_t*)(ws + QCAT_OFF);
  half_t* kcat = (half_t*)(ws + KCAT_OFF);
  half_t* vt = (half_t*)(ws + VT_OFF);
  float* out = (float*)d_out;

  // 1. split X and W (fp16)
  k_split_x<<<dim3(MX * 1024 / 1024), dim3(256), 0, stream>>>(X, xcat);
  k_split_wt<<<dim3(16, 16, 3), dim3(256), 0, stream>>>(Wq, Wk, Wv, wt);

  // 2a. fused QK projection: M=8192, N=2048 (Wq|Wk rows), K=2048 (2-term)
  k_gemm<EP_QK><<<dim3(16, 64, 1), dim3(256), 0, stream>>>(
      xcat, 0LL, KCAT, wt, 0LL, KCAT, qcat, 0LL, 0, KCAT, kcat);

  // 2b. V projection: M=8192, N=1024, K=1024 (1-term: x_hi . Wv_hi)
  k_gemm<EP_VT><<<dim3(8, 64, 1), dim3(256), 0, stream>>>(
      xcat, 0LL, KCAT, wt + 2 * 1024 * KCAT, 0LL, KCAT, vt, 0LL, 0, 1024, nullptr);

  // 3. scores S = Q K^T (fp16 2-term), fp32 out: per batch M=N=2048
  k_gemm<EP_F32><<<dim3(16, 16, 4), dim3(256), 0, stream>>>(
      qcat, (long long)2048 * KCAT, KCAT, kcat, (long long)2048 * KCAT, KCAT,
      Sbuf, (long long)2048 * 2048, 2048, KCAT, nullptr);

  // 4. softmax (fp32 row -> fp16 row; row stride becomes 4096 halves)
  k_softmax<<<dim3(2048), dim3(256), 0, stream>>>(Sbuf);

  // 5. O = P V (plain fp16), fp32 out: per batch M=2048, N=1024, K=2048
  k_gemm<EP_F32><<<dim3(8, 16, 4), dim3(256), 0, stream>>>(
      (const half_t*)Sbuf, (long long)2048 * 4096, 4096,
      vt, (long long)1024 * 2048, 2048,
      out, (long long)2048 * 1024, 1024, 2048, nullptr);
}